// Round 16
// baseline (266.973 us; speedup 1.0000x reference)
//
#include <hip/hip_runtime.h>
#include <cstdint>

#define TEMP_C 20.0f

typedef float f32x4 __attribute__((ext_vector_type(4)));
typedef float f32x16 __attribute__((ext_vector_type(16)));
typedef int i32x4 __attribute__((ext_vector_type(4)));
typedef int i32x8 __attribute__((ext_vector_type(8)));

// fp32 -> bf16 round-to-nearest-even
__device__ __forceinline__ unsigned short f2bf(float f) {
  union { float f; unsigned int u; } v; v.f = f;
  unsigned int r = v.u + 0x7FFFu + ((v.u >> 16) & 1u);
  return (unsigned short)(r >> 16);
}
__device__ __forceinline__ float bf2f(unsigned short b) {
  union { unsigned int u; float f; } v; v.u = ((unsigned int)b) << 16;
  return v.f;
}

// fp32 -> OCP e4m3fn, RTNE, clamp to +-448
__device__ __forceinline__ unsigned char f2e4m3(float f) {
  unsigned u = __float_as_uint(f);
  unsigned s = (u >> 24) & 0x80u;
  float a = fminf(fabsf(f), 448.0f);
  if (a < 0.015625f) {
    int d = (int)rintf(a * 512.0f);
    return (unsigned char)(s | (unsigned)d);
  }
  unsigned au = __float_as_uint(a);
  unsigned r = au + 0xFFFFFu + ((au >> 20) & 1u);
  int Ep = (int)(r >> 23) - 127;
  if (Ep > 8) return (unsigned char)(s | 0x7E);
  unsigned m = (r >> 20) & 7u;
  return (unsigned char)(s | ((unsigned)(Ep + 7) << 3) | m);
}

// fp32 -> e2m1 nibble (round to nearest of {0,.5,1,1.5,2,3,4,6}, sign bit3)
__device__ __forceinline__ unsigned f2e2m1(float f) {
  unsigned s = (__float_as_uint(f) >> 28) & 8u;
  float a = fabsf(f);
  unsigned n = (unsigned)(a >= 0.25f) + (a >= 0.75f) + (a >= 1.25f) +
               (a >= 1.75f) + (a >= 2.5f) + (a >= 3.5f) + (a >= 5.0f);
  return s | n;
}

// async global->LDS, 16B per lane (dest = wave-uniform base + lane*16)
__device__ __forceinline__ void gload_lds16(const void* g, void* l) {
  __builtin_amdgcn_global_load_lds(
      (__attribute__((address_space(1))) void*)(g),
      (__attribute__((address_space(3))) void*)(l), 16, 0, 0);
}

// ---------------------------------------------------------------------------
// 1) fused transpose + FP4 pack + per-(pixel, 32ch-group) sumsq partials.
//    (r15 verified, unchanged)
__global__ __launch_bounds__(256) void tpose2_f4_k(
    const float* __restrict__ X4, const float* __restrict__ X3,
    unsigned char* __restrict__ T, float* __restrict__ part)
{
  __shared__ float tile[32][33];
  __shared__ float red2[8][33];
  const int tx = threadIdx.x, ty = threadIdx.y;
  const int y = blockIdx.y;
  const float* X; int c0;
  if (y < 64) { X = X4; c0 = y * 32; }
  else        { X = X3; c0 = (y - 64) * 32; }
  const int p0 = blockIdx.x * 32;
  #pragma unroll
  for (int i = 0; i < 4; ++i) {
    int c = c0 + ty + i * 8, p = p0 + tx;
    tile[ty + i * 8][tx] = (p < 3600) ? X[(size_t)c * 3600 + p] : 0.f;
  }
  __syncthreads();
  {
    float s = 0.f;
    #pragma unroll
    for (int k = 0; k < 4; ++k) { float v = tile[ty * 4 + k][tx]; s += v * v; }
    red2[ty][tx] = s;
  }
  if (tx < 16) {
    const size_t gbase = (size_t)y * 3840 * 16 + tx;
    #pragma unroll
    for (int i = 0; i < 4; ++i) {
      int p = p0 + ty + i * 8;
      if (p < 3600) {
        unsigned lo = f2e2m1(tile[2 * tx][ty + i * 8]);
        unsigned hi = f2e2m1(tile[2 * tx + 1][ty + i * 8]);
        T[gbase + (size_t)p * 16] = (unsigned char)(lo | (hi << 4));
      }
    }
  }
  __syncthreads();
  if (ty == 0 && p0 + tx < 3600) {
    float s = 0.f;
    #pragma unroll
    for (int j = 0; j < 8; ++j) s += red2[j][tx];
    part[(size_t)y * 3600 + p0 + tx] = s;
  }
}

// 1b) finish: inv4[p] = 1/||x4_p||, inv3[p] = 1/||x3_p|| from 96 partials
__global__ __launch_bounds__(256) void norm_fin_k(
    const float* __restrict__ part, float* __restrict__ inv4,
    float* __restrict__ inv3)
{
  const int p = blockIdx.x * 256 + threadIdx.x;
  if (p >= 3600) return;
  float s4 = 0.f, s3 = 0.f;
  #pragma unroll
  for (int y = 0; y < 64; ++y) s4 += part[(size_t)y * 3600 + p];
  #pragma unroll
  for (int y = 64; y < 96; ++y) s3 += part[(size_t)y * 3600 + p];
  inv4[p] = 1.0f / fmaxf(sqrtf(s4), 1e-12f);
  inv3[p] = 1.0f / fmaxf(sqrtf(s3), 1e-12f);
}

// ---------------------------------------------------------------------------
// 2) V cast to fp8, K-group-major over s
__global__ void castv_f8_k(const float* __restrict__ X, unsigned char* __restrict__ V8)
{
  int i = blockIdx.x * 256 + threadIdx.x;
  if (i >= 512 * 3600) return;
  int c = i / 3600, s = i - c * 3600;
  V8[((size_t)(s >> 4) * 512 + c) * 16 + (s & 15)] = f2e4m3(X[i]);
}

// ---------------------------------------------------------------------------
// 3) 128x128 MX-FP4 DUAL-LEVEL GEMM: one pass over all 96 k-groups
//    (tiles 0-15 = level4 -> acc4, 16-23 = level3 -> acc3, uniform branch).
//    Epilogue assembles the final LOGIT:
//      L[q][s] = TEMP*( w0*dot4*invq4[q]*invs4[s] + w1*dot3*invq3[q]*invs3[s] )
//    written bf16 once — eliminates the separate L3 matrix (28MB write +
//    28MB read per batch) and softmax's dual-stream scaling.
//    Same r11/r15-verified staging/FRAG4/MFMA4 pieces. acc doubles ->
//    launch_bounds(256,2) (measured effective occupancy was ~2 blocks anyway).
__global__ __launch_bounds__(256, 2) void gemm128_f4_dual(
    const unsigned char* __restrict__ A, const unsigned char* __restrict__ B,
    unsigned short* __restrict__ C, int MPr, int ldc, int nbn,
    const float* __restrict__ invq4, const float* __restrict__ invq3,
    const float* __restrict__ invs4, const float* __restrict__ invs3,
    const float* __restrict__ wch)
{
  __shared__ __align__(16) unsigned char As[2][8192];   // [4 g][128 rows][16B]
  __shared__ __align__(16) unsigned char Bs[2][8192];

  const int tid  = threadIdx.x;
  const int lane = tid & 63;
  const int wave = tid >> 6;
  const int wrow = wave >> 1;
  const int wcol = wave & 1;

  // XCD-aware bijective block remap (m204)
  const int nwg = gridDim.x;
  const int q8 = nwg >> 3, r8 = nwg & 7;
  const int xcd = blockIdx.x & 7, bidx = blockIdx.x >> 3;
  const int wg = (xcd < r8 ? xcd * (q8 + 1) : r8 * (q8 + 1) + (xcd - r8) * q8) + bidx;
  const long Arow0 = (long)(wg / nbn) * 128;
  const long Brow0 = (long)(wg % nbn) * 128;

  const unsigned char* sA[2];
  const unsigned char* sB[2];
  #pragma unroll
  for (int q = 0; q < 2; ++q) {
    const int c = q * 256 + tid;
    const int g = c >> 7, r = c & 127;
    sA[q] = A + ((long)g * MPr + Arow0 + r) * 16;
    sB[q] = B + ((long)g * MPr + Brow0 + r) * 16;
  }
  const long kstride = (long)MPr * 16 * 4;   // 4 groups (=128 fp4 k) per tile

  #define STAGE(tt) do { const int _sl = (tt) & 1; const long _ko = (long)(tt) * kstride; \
    gload_lds16(sA[0] + _ko, &As[_sl][tid * 16]);              \
    gload_lds16(sA[1] + _ko, &As[_sl][(256 + tid) * 16]);      \
    gload_lds16(sB[0] + _ko, &Bs[_sl][tid * 16]);              \
    gload_lds16(sB[1] + _ko, &Bs[_sl][(256 + tid) * 16]);      \
  } while (0)

  const int l31 = lane & 31, lk = lane >> 5;
  const int arow0 = (wrow * 64 + l31) * 16;
  const int brow0 = (wcol * 64 + l31) * 16;

  f32x16 acc4[2][2] = {};
  f32x16 acc3[2][2] = {};
  const int NT = 24;   // 16 level4 tiles + 8 level3 tiles (96 groups total)

  STAGE(0);

  for (int t = 0; t < NT; ++t) {
    const int sl = t & 1;
    if (t + 1 < NT) {
      STAGE(t + 1);
      asm volatile("s_waitcnt vmcnt(4)" ::: "memory");
    } else {
      asm volatile("s_waitcnt vmcnt(0)" ::: "memory");
    }
    asm volatile("s_barrier" ::: "memory");

    const unsigned char* Ap = As[sl];
    const unsigned char* Bp = Bs[sl];
    #define FRAG4(dst, base, rowb, g) do {                       \
      i32x4 _v = *(const i32x4*)((base) + ((g) << 11) + (rowb)); \
      dst[0]=_v[0]; dst[1]=_v[1]; dst[2]=_v[2]; dst[3]=_v[3];    \
      dst[4]=_v[0]; dst[5]=_v[1]; dst[6]=_v[2]; dst[7]=_v[3];    \
    } while (0)
    #define MFMA4(a, b, d) \
      d = __builtin_amdgcn_mfma_scale_f32_32x32x64_f8f6f4( \
          a, b, d, 4, 4, 0, 127, 0, 127)

    if (t < 16) {
      #pragma unroll
      for (int h = 0; h < 2; ++h) {
        const int g = h * 2 + lk;
        i32x8 a0, a1, b0, b1;
        FRAG4(a0, Ap, arow0, g); FRAG4(a1, Ap, arow0 + 512, g);
        FRAG4(b0, Bp, brow0, g); FRAG4(b1, Bp, brow0 + 512, g);
        __builtin_amdgcn_s_setprio(1);
        MFMA4(a0, b0, acc4[0][0]); MFMA4(a0, b1, acc4[0][1]);
        MFMA4(a1, b0, acc4[1][0]); MFMA4(a1, b1, acc4[1][1]);
        __builtin_amdgcn_s_setprio(0);
      }
    } else {
      #pragma unroll
      for (int h = 0; h < 2; ++h) {
        const int g = h * 2 + lk;
        i32x8 a0, a1, b0, b1;
        FRAG4(a0, Ap, arow0, g); FRAG4(a1, Ap, arow0 + 512, g);
        FRAG4(b0, Bp, brow0, g); FRAG4(b1, Bp, brow0 + 512, g);
        __builtin_amdgcn_s_setprio(1);
        MFMA4(a0, b0, acc3[0][0]); MFMA4(a0, b1, acc3[0][1]);
        MFMA4(a1, b0, acc3[1][0]); MFMA4(a1, b1, acc3[1][1]);
        __builtin_amdgcn_s_setprio(0);
      }
    }
    #undef FRAG4
    #undef MFMA4
    asm volatile("s_barrier" ::: "memory");
  }
  #undef STAGE

  // epilogue: assemble logits. col=lane&31 (+0/+32), row=(reg&3)+8*(reg>>2)+4*lk
  const float w0 = TEMP_C * wch[0];
  const float w1 = TEMP_C * wch[1];
  const long col0 = Brow0 + wcol * 64 + l31;
  const float s40 = invs4[col0],      s30 = invs3[col0];
  const float s41 = invs4[col0 + 32], s31 = invs3[col0 + 32];
  #pragma unroll
  for (int m = 0; m < 2; ++m) {
    const long rowb = Arow0 + wrow * 64 + m * 32;
    #pragma unroll
    for (int g4 = 0; g4 < 4; ++g4) {
      #pragma unroll
      for (int r4 = 0; r4 < 4; ++r4) {
        const long row = rowb + r4 + 8 * g4 + 4 * lk;
        const float q4 = w0 * invq4[row], q3 = w1 * invq3[row];
        unsigned short* cp = C + row * (long)ldc + col0;
        const int e = g4 * 4 + r4;
        cp[0]  = f2bf(q4 * s40 * acc4[m][0][e] + q3 * s30 * acc3[m][0][e]);
        cp[32] = f2bf(q4 * s41 * acc4[m][1][e] + q3 * s31 * acc3[m][1][e]);
      }
    }
  }
}

// ---------------------------------------------------------------------------
// 4) PV MX-fp8 GEMM, deep-pipelined (r14 verified, unchanged).
__global__ __launch_bounds__(256, 2) void pv_f8_k(
    const unsigned char* __restrict__ Att, const unsigned char* __restrict__ V,
    unsigned short* __restrict__ P, int accumulate)
{
  __shared__ __align__(16) unsigned char As[4][4096];
  __shared__ __align__(16) unsigned char As2[4][4096];
  __shared__ __align__(16) unsigned char Bs[4][4096];
  __shared__ __align__(16) unsigned char Bs2[4][4096];

  const int tid  = threadIdx.x;
  const int lane = tid & 63;
  const int wave = tid >> 6;
  const int wrow = wave >> 1;
  const int wcol = wave & 1;

  const int xcd = blockIdx.x & 7, bidx = blockIdx.x >> 3;
  const int wg = xcd * 45 + bidx;
  const int x = wg / 12, rem = wg % 12;
  const int y = rem & 3, z = rem >> 2;
  const long Arow0 = (long)x * 128;
  const long Brow0 = (long)y * 128;
  P += (long)z * 3840 * 512;

  const unsigned char* sA[2];
  const unsigned char* sB[2];
  #pragma unroll
  for (int q = 0; q < 2; ++q) {
    const int c = q * 256 + tid;
    const int g = c >> 7, r = c & 127;
    sA[q] = Att + ((long)(z * 80 + g) * 3840 + Arow0 + r) * 16;
    sB[q] = V   + ((long)(z * 80 + g) * 512  + Brow0 + r) * 16;
  }
  const long ksA = 3840L * 16 * 4;
  const long ksB = 512L * 16 * 4;

  #define STAGE(tt) do { const int _sl = (tt) & 3;                      \
    gload_lds16(sA[0] + (long)(tt) * ksA, &As[_sl][tid * 16]);          \
    gload_lds16(sA[1] + (long)(tt) * ksA, &As2[_sl][tid * 16]);         \
    gload_lds16(sB[0] + (long)(tt) * ksB, &Bs[_sl][tid * 16]);          \
    gload_lds16(sB[1] + (long)(tt) * ksB, &Bs2[_sl][tid * 16]);         \
  } while (0)

  const int l31 = lane & 31, lk = lane >> 5;
  const int arow0 = (wrow * 64 + l31) * 16;
  const int brow0 = (wcol * 64 + l31) * 16;

  f32x16 acc[2][2] = {};
  const int NT = 20;

  STAGE(0); STAGE(1); STAGE(2);

  for (int t = 0; t < NT; ++t) {
    const int sl = t & 3;
    const int rem_t = NT - 1 - t;
    if (rem_t >= 2)      asm volatile("s_waitcnt vmcnt(8)" ::: "memory");
    else if (rem_t == 1) asm volatile("s_waitcnt vmcnt(4)" ::: "memory");
    else                 asm volatile("s_waitcnt vmcnt(0)" ::: "memory");
    asm volatile("s_barrier" ::: "memory");
    if (t + 3 < NT) STAGE(t + 3);

    const unsigned char* ApL = lk ? As2[sl] : As[sl];
    const unsigned char* BpL = lk ? Bs2[sl] : Bs[sl];
    #define LDF(base, rowb, s) (*(const i32x4*)((base) + (((s) << 11) + (rowb))))
    #define FRAG(dst, base, rowb) do {                  \
      i32x4 _lo = LDF(base, rowb, 0);                   \
      i32x4 _hi = LDF(base, rowb, 1);                   \
      dst[0]=_lo[0]; dst[1]=_lo[1]; dst[2]=_lo[2]; dst[3]=_lo[3]; \
      dst[4]=_hi[0]; dst[5]=_hi[1]; dst[6]=_hi[2]; dst[7]=_hi[3]; \
    } while (0)
    #define MFMA8(a, b, m, n) \
      acc[m][n] = __builtin_amdgcn_mfma_scale_f32_32x32x64_f8f6f4( \
          a, b, acc[m][n], 0, 0, 0, 127, 0, 127)

    i32x8 a0, a1, b0, b1;
    FRAG(a0, ApL, arow0); FRAG(a1, ApL, arow0 + 512);
    FRAG(b0, BpL, brow0); FRAG(b1, BpL, brow0 + 512);
    asm volatile("s_waitcnt lgkmcnt(0)" ::: "memory");
    __builtin_amdgcn_sched_barrier(0);
    __builtin_amdgcn_s_setprio(1);
    MFMA8(a0, b0, 0, 0); MFMA8(a0, b1, 0, 1);
    MFMA8(a1, b0, 1, 0); MFMA8(a1, b1, 1, 1);
    __builtin_amdgcn_s_setprio(0);
    #undef LDF
    #undef FRAG
    #undef MFMA8
  }
  #undef STAGE

  #pragma unroll
  for (int m = 0; m < 2; ++m) {
    const long rowb = Arow0 + wrow * 64 + m * 32;
    #pragma unroll
    for (int g4 = 0; g4 < 4; ++g4) {
      #pragma unroll
      for (int r4 = 0; r4 < 4; ++r4) {
        const long row = rowb + r4 + 8 * g4 + 4 * lk;
        unsigned short* cp = P + row * 512 + Brow0 + wcol * 64 + l31;
        float v0 = acc[m][0][g4 * 4 + r4];
        float v1 = acc[m][1][g4 * 4 + r4];
        if (accumulate) { v0 += bf2f(cp[0]); v1 += bf2f(cp[32]); }
        cp[0]  = f2bf(v0);
        cp[32] = f2bf(v1);
      }
    }
  }
}

// ---------------------------------------------------------------------------
// 5) row softmax (logits pre-assembled): single bf16 stream -> fp8 attn*448
__global__ __launch_bounds__(256) void softmax_rows_k(
    const unsigned short* __restrict__ L, unsigned char* __restrict__ Att)
{
  const int q = blockIdx.x;
  const unsigned short* row = L + (size_t)q * 3840;
  const int tid = threadIdx.x;
  float v[15];
  float mx = -1e30f;
  #pragma unroll
  for (int j = 0; j < 15; ++j) {
    int s = tid + j * 256;
    float x = (s < 3600) ? bf2f(row[s]) : -1e30f;
    v[j] = x;
    mx = fmaxf(mx, x);
  }
  #pragma unroll
  for (int o = 32; o > 0; o >>= 1) mx = fmaxf(mx, __shfl_xor(mx, o));
  __shared__ float wmax[4], wsum[4];
  if ((tid & 63) == 0) wmax[tid >> 6] = mx;
  __syncthreads();
  mx = fmaxf(fmaxf(wmax[0], wmax[1]), fmaxf(wmax[2], wmax[3]));
  float sum = 0.f;
  #pragma unroll
  for (int j = 0; j < 15; ++j) {
    int s = tid + j * 256;
    float e = (s < 3600) ? __expf(v[j] - mx) : 0.f;
    v[j] = e;
    sum += e;
  }
  #pragma unroll
  for (int o = 32; o > 0; o >>= 1) sum += __shfl_xor(sum, o);
  if ((tid & 63) == 0) wsum[tid >> 6] = sum;
  __syncthreads();
  sum = wsum[0] + wsum[1] + wsum[2] + wsum[3];
  const float inv448 = 448.0f / sum;
  #pragma unroll
  for (int j = 0; j < 15; ++j) {
    int s = tid + j * 256;
    unsigned char b = (s < 3600) ? f2e4m3(v[j] * inv448) : (unsigned char)0;
    Att[((size_t)(s >> 4) * 3840 + q) * 16 + (s & 15)] = b;
  }
}

// ---------------------------------------------------------------------------
// 6) out[c][p] = 0.5*f_q[c][p] + (0.25/448)*sum_z P[z][p][c]  (3 bf16 partials)
__global__ __launch_bounds__(256) void final_blend_k(
    const unsigned short* __restrict__ P, const float* __restrict__ fq,
    float* __restrict__ out)
{
  __shared__ float t[32][33];
  const int tx = threadIdx.x, ty = threadIdx.y;
  const int p0 = blockIdx.x * 32, c0 = blockIdx.y * 32;
  const long ZC = 3840L * 512;
  #pragma unroll
  for (int i = 0; i < 4; ++i) {
    int p = p0 + ty + i * 8, c = c0 + tx;
    float s = 0.f;
    if (p < 3600) {
      size_t o = (size_t)p * 512 + c;
      #pragma unroll
      for (int z = 0; z < 3; ++z) s += bf2f(P[o + (size_t)z * ZC]);
    }
    t[ty + i * 8][tx] = s;
  }
  __syncthreads();
  const float wts = 0.25f / 448.0f;
  #pragma unroll
  for (int i = 0; i < 4; ++i) {
    int c = c0 + ty + i * 8, p = p0 + tx;
    if (p < 3600) {
      size_t o = (size_t)c * 3600 + p;
      out[o] = 0.5f * fq[o] + wts * t[tx][ty + i * 8];
    }
  }
}

// ---------------------------------------------------------------------------
extern "C" void kernel_launch(void* const* d_in, const int* in_sizes, int n_in,
                              void* d_out, int out_size, void* d_ws, size_t ws_size,
                              hipStream_t stream) {
  const float* fq3 = (const float*)d_in[0];
  const float* fq4 = (const float*)d_in[1];
  const float* fs3 = (const float*)d_in[2];
  const float* fs4 = (const float*)d_in[3];
  const float* f_q = (const float*)d_in[4];
  const float* f_s = (const float*)d_in[5];
  const float* wch = (const float*)d_in[6];
  float* out = (float*)d_out;

  const size_t HW = 3600, MP = 3840, CH = 512;
  const size_t NG = 96;

  // workspace (~80 MB)
  unsigned char* QT4 = (unsigned char*)d_ws;          // (96, MP, 16B) fp4 query (raw)
  unsigned char* ST4 = QT4 + NG * MP * 16;            // (96, MP, 16B) fp4 support
  unsigned char* V8  = ST4 + NG * MP * 16;            // (MP/16, CH, 16B) fp8 V
  unsigned short* L  = (unsigned short*)(V8 + MP * CH);   // (MP,MP) bf16 LOGITS
  unsigned char* Att8 = (unsigned char*)(L + MP * MP);    // (MP/16, MP, 16B) fp8 attn*448
  unsigned short* Pb = (unsigned short*)(Att8 + MP * MP); // 3 x (MP,CH) bf16 partials
  float* invq4 = (float*)(Pb + 3 * MP * CH);          // 4 x 3600 norm inverses
  float* invq3 = invq4 + HW;
  float* invs4 = invq3 + HW;
  float* invs3 = invs4 + HW;
  float* partQ = invs3 + HW;                          // 96 x 3600
  float* partS = partQ + 96 * HW;                     // 96 x 3600

  dim3 tb(32, 8);
  tpose2_f4_k<<<dim3(113, 96), tb, 0, stream>>>(fq4, fq3, QT4, partQ);
  norm_fin_k<<<15, 256, 0, stream>>>(partQ, invq4, invq3);

  for (int b = 0; b < 2; ++b) {
    castv_f8_k<<<7200, 256, 0, stream>>>(f_s + (size_t)b * CH * HW, V8);
    tpose2_f4_k<<<dim3(113, 96), tb, 0, stream>>>(
        fs4 + (size_t)b * 2048 * HW, fs3 + (size_t)b * 1024 * HW, ST4, partS);
    norm_fin_k<<<15, 256, 0, stream>>>(partS, invs4, invs3);

    // one dual-level GEMM: logits assembled in the epilogue (bf16)
    gemm128_f4_dual<<<900, 256, 0, stream>>>(QT4, ST4, L, 3840, 3840, 30,
                                             invq4, invq3, invs4, invs3, wch);

    softmax_rows_k<<<3600, 256, 0, stream>>>(L, Att8);

    // PV split-K=3, deep-pipelined, XCD-chunked (360 blocks)
    pv_f8_k<<<360, 256, 0, stream>>>(Att8, V8, Pb, b);
  }

  final_blend_k<<<dim3(113, 16), tb, 0, stream>>>(Pb, f_q, out);
}